// Round 4
// baseline (2857.707 us; speedup 1.0000x reference)
//
#include <hip/hip_runtime.h>
#include <hip/hip_bf16.h>

typedef __bf16 bf16_t;
typedef __bf16 bf16x4 __attribute__((ext_vector_type(4)));
typedef __bf16 bf16x8 __attribute__((ext_vector_type(8)));
typedef float  f32x4  __attribute__((ext_vector_type(4)));

#define NH    6
#define CH    192
#define HW    112
#define SHIFT 3

// LDS strides (bf16 elems). XLD=200 -> 400B row step; ULD=72 -> 144B row step.
#define XLD 200
#define ULD 72

#define X_OFF   0
#define K_OFF   (64 * XLD)            // 12800
// P/VOt overlay the dead K region after the B2 barrier; VOt tail extends past K.
#define P_OFF   K_OFF                 // 64 x ULD   = 4608 elems
#define VOT_OFF (K_OFF + 64 * ULD)    // 192 x ULD  = 13824 elems
#define LDS_ELEMS (VOT_OFF + 192 * ULD)  // 31232
#define LDS_BYTES (LDS_ELEMS * 2)        // 62464 B -> 2 blocks/CU guaranteed

// ws layout: wts[0]=Wq^T, wts[1]=Wk^T, wts[2]=U^T (each NH*CH*CH bf16), then bu f32[NH*CH]
#define BU_OFF_BYTES (3 * NH * CH * CH * 2)

// ---- prep: Wq/Wk transposed to bf16 ---------------------------------------
__global__ void prep_w(const float* __restrict__ Wq, const float* __restrict__ Wk,
                       bf16_t* __restrict__ out) {
  int idx = blockIdx.x * 256 + threadIdx.x;
  const int per = NH * CH * CH;
  if (idx >= 2 * per) return;
  int m = idx / per, r = idx % per;
  int h = r / (CH * CH), r2 = r % (CH * CH);
  int a = r2 / CH, k = r2 % CH;
  const float* W = m ? Wk : Wq;
  out[idx] = (bf16_t)W[(k * NH + h) * CH + a];   // wts[m][h][d_out][c_in]
}

// ---- prep: U^h = Wv^h x Wo^h (value/out-proj fusion), stored U^T[c_out][c_in]
__global__ void prep_u(const float* __restrict__ Wv, const float* __restrict__ Wo,
                       bf16_t* __restrict__ u_out) {
  __shared__ float wv_row[CH];
  int h = blockIdx.x / CH, ci = blockIdx.x % CH;
  int t = threadIdx.x;                            // c_out
  wv_row[t] = Wv[(ci * NH + h) * CH + t];
  __syncthreads();
  float acc = 0.f;
  for (int d = 0; d < CH; ++d)
    acc += wv_row[d] * Wo[(h * CH + d) * CH + t];
  u_out[(h * CH + t) * CH + ci] = (bf16_t)acc;
}

// ---- prep: bu^h = bv^h x Wo^h ---------------------------------------------
__global__ void prep_bu(const float* __restrict__ bv, const float* __restrict__ Wo,
                        float* __restrict__ bu) {
  int h = blockIdx.x, c = threadIdx.x;
  float acc = 0.f;
  for (int d = 0; d < CH; ++d)
    acc += bv[h * CH + d] * Wo[(h * CH + d) * CH + c];
  bu[h * CH + c] = acc;
}

// ---- fused swin block: one workgroup per 7x7 window, 8 waves, 2 blocks/CU --
__global__ __launch_bounds__(512, 4) void swin_fused(
    const float* __restrict__ x,
    const float* __restrict__ bq, const float* __restrict__ bk,
    const float* __restrict__ bo,
    const bf16_t* __restrict__ wts, const float* __restrict__ bu,
    float* __restrict__ out) {
  extern __shared__ char smem_raw[];
  bf16_t* lds  = (bf16_t*)smem_raw;
  bf16_t* Xl   = lds + X_OFF;
  bf16_t* Kl   = lds + K_OFF;
  bf16_t* Pl   = lds + P_OFF;     // overlay (valid after B2)
  bf16_t* VOtl = lds + VOT_OFF;   // overlay (valid after B2)

  const int tid  = threadIdx.x;
  const int wave = tid >> 6;           // 0..7
  const int lane = tid & 63;
  const int l15  = lane & 15;
  const int lg   = lane >> 4;          // 0..3

  const int blk = blockIdx.x;
  const int b   = blk >> 8;
  const int rem = blk & 255;
  const int wi  = rem >> 4, wj = rem & 15;

  // zero pad rows 49..63 of X
  for (int idx = tid; idx < 15 * 100; idx += 512) {
    int row = 49 + idx / 100, c2 = (idx % 100) * 2;
    *(unsigned int*)&Xl[row * XLD + c2] = 0u;
  }
  // stage window tokens (roll -3,-3 folded into the gather), f32 -> bf16
  for (int idx = tid; idx < 49 * 48; idx += 512) {
    int t = idx / 48, q4 = idx % 48;
    int hs = wi * 7 + t / 7 + SHIFT; if (hs >= HW) hs -= HW;
    int ws2 = wj * 7 + t % 7 + SHIFT; if (ws2 >= HW) ws2 -= HW;
    const float4 v = *(const float4*)&x[(((b * HW + hs) * HW) + ws2) * CH + q4 * 4];
    bf16x4 pk = { (bf16_t)v.x, (bf16_t)v.y, (bf16_t)v.z, (bf16_t)v.w };
    *(bf16x4*)&Xl[t * XLD + q4 * 4] = pk;
  }

  const int wc = wave & 3;             // phase-Y c-block (3 tiles each)
  const int wt = wave >> 2;            // phase-Y t-block (2 tiles each)
  f32x4 yacc[3][2] = {};               // persistent output accumulators

  for (int h = 0; h < NH; ++h) {
    __syncthreads();
    // ---- Phase A: waves 0-3: Q self-tile into REGISTERS (no LDS);
    //               waves 4-7: K^T-GEMM into LDS.
    bf16x4 qf[12];                     // Q[t=wave*16+l15][d=md*16+lg*4+r]
    if (wave < 4) {
      const bf16_t* wq_p = wts + (h * CH * CH);
      f32x4 accq[12] = {};
#pragma unroll
      for (int ks = 0; ks < 6; ++ks) {
        bf16x8 bfr = *(const bf16x8*)&Xl[(wave * 16 + l15) * XLD + ks * 32 + lg * 8];
#pragma unroll
        for (int md = 0; md < 12; ++md) {
          bf16x8 af = *(const bf16x8*)&wq_p[(md * 16 + l15) * CH + ks * 32 + lg * 8];
          accq[md] = __builtin_amdgcn_mfma_f32_16x16x32_bf16(af, bfr, accq[md], 0, 0, 0);
        }
      }
#pragma unroll
      for (int md = 0; md < 12; ++md) {
        const f32x4 bb = *(const f32x4*)&bq[h * CH + md * 16 + lg * 4];
        bf16x4 pk = { (bf16_t)(accq[md][0] + bb[0]), (bf16_t)(accq[md][1] + bb[1]),
                      (bf16_t)(accq[md][2] + bb[2]), (bf16_t)(accq[md][3] + bb[3]) };
        qf[md] = pk;
      }
    } else {
      const int w2 = wave - 4;
      const bf16_t* wk_p = wts + ((NH + h) * CH * CH);
      const float* bias = bk + h * CH;
      f32x4 acc[3][4] = {};
#pragma unroll
      for (int ks = 0; ks < 6; ++ks) {
        bf16x8 af[3], bfr[4];
#pragma unroll
        for (int mi = 0; mi < 3; ++mi) {
          int d = (w2 * 3 + mi) * 16 + l15;
          af[mi] = *(const bf16x8*)&wk_p[d * CH + ks * 32 + lg * 8];
        }
#pragma unroll
        for (int ni = 0; ni < 4; ++ni)
          bfr[ni] = *(const bf16x8*)&Xl[(ni * 16 + l15) * XLD + ks * 32 + lg * 8];
#pragma unroll
        for (int mi = 0; mi < 3; ++mi)
#pragma unroll
          for (int ni = 0; ni < 4; ++ni)
            acc[mi][ni] = __builtin_amdgcn_mfma_f32_16x16x32_bf16(af[mi], bfr[ni], acc[mi][ni], 0, 0, 0);
      }
#pragma unroll
      for (int mi = 0; mi < 3; ++mi) {
        int d0 = (w2 * 3 + mi) * 16 + lg * 4;
        float b0 = bias[d0], b1 = bias[d0 + 1], b2 = bias[d0 + 2], b3 = bias[d0 + 3];
#pragma unroll
        for (int ni = 0; ni < 4; ++ni) {
          int t = ni * 16 + l15;
          bf16x4 pk = { (bf16_t)(acc[mi][ni][0] + b0), (bf16_t)(acc[mi][ni][1] + b1),
                        (bf16_t)(acc[mi][ni][2] + b2), (bf16_t)(acc[mi][ni][3] + b3) };
          *(bf16x4*)&Kl[t * XLD + d0] = pk;
        }
      }
    }
    __syncthreads();
    // ---- Phase B: waves 0-3: scores + in-register softmax (Q from regs,
    //               K read with the MATCHING permuted k-slot order);
    //               waves 4-7: VO-GEMM (X x U^h) into registers.
    f32x4 vacc[4][3] = {};
    bf16x4 psave[4];
    const bf16_t* U_h = wts + ((2 * NH + h) * CH * CH);
    if (wave < 4) {
      f32x4 sacc[4] = {};
#pragma unroll
      for (int ks = 0; ks < 6; ++ks) {
        // B-frag: slots 0-3 = Q[t][ks*32+lg*4+r], slots 4-7 = Q[t][ks*32+16+lg*4+r]
        bf16x8 bq8 = __builtin_shufflevector(qf[2 * ks], qf[2 * ks + 1], 0, 1, 2, 3, 4, 5, 6, 7);
#pragma unroll
        for (int mj = 0; mj < 4; ++mj) {
          // A-frag with the SAME k-slot permutation (two b64 reads, d and d+16)
          const bf16_t* kr = &Kl[(mj * 16 + l15) * XLD + ks * 32 + lg * 4];
          bf16x4 k0 = *(const bf16x4*)kr;
          bf16x4 k1 = *(const bf16x4*)(kr + 16);
          bf16x8 ak = __builtin_shufflevector(k0, k1, 0, 1, 2, 3, 4, 5, 6, 7);
          sacc[mj] = __builtin_amdgcn_mfma_f32_16x16x32_bf16(ak, bq8, sacc[mj], 0, 0, 0);
        }
      }
      const float scale = 0.07216878364870322f;  // 1/sqrt(192)
      float mx = -1e30f;
#pragma unroll
      for (int mj = 0; mj < 4; ++mj)
#pragma unroll
        for (int r = 0; r < 4; ++r) {
          int j = mj * 16 + lg * 4 + r;
          if (j < 49) mx = fmaxf(mx, sacc[mj][r]);
        }
      mx = fmaxf(mx, __shfl_xor(mx, 16));
      mx = fmaxf(mx, __shfl_xor(mx, 32));
      float p[4][4];
      float sum = 0.f;
#pragma unroll
      for (int mj = 0; mj < 4; ++mj)
#pragma unroll
        for (int r = 0; r < 4; ++r) {
          int j = mj * 16 + lg * 4 + r;
          float e = (j < 49) ? __expf((sacc[mj][r] - mx) * scale) : 0.f;
          p[mj][r] = e;
          sum += e;
        }
      sum += __shfl_xor(sum, 16);
      sum += __shfl_xor(sum, 32);
      float inv = 1.f / sum;
#pragma unroll
      for (int mj = 0; mj < 4; ++mj) {
        bf16x4 pk = { (bf16_t)(p[mj][0] * inv), (bf16_t)(p[mj][1] * inv),
                      (bf16_t)(p[mj][2] * inv), (bf16_t)(p[mj][3] * inv) };
        psave[mj] = pk;
      }
    } else {
      const int wv = wave - 4;
#pragma unroll
      for (int ks = 0; ks < 6; ++ks) {
        bf16x8 af[4], bfr[3];
#pragma unroll
        for (int mi = 0; mi < 4; ++mi)
          af[mi] = *(const bf16x8*)&Xl[(mi * 16 + l15) * XLD + ks * 32 + lg * 8];
#pragma unroll
        for (int ni = 0; ni < 3; ++ni) {
          int c = (wv * 3 + ni) * 16 + l15;
          bfr[ni] = *(const bf16x8*)&U_h[c * CH + ks * 32 + lg * 8];
        }
#pragma unroll
        for (int mi = 0; mi < 4; ++mi)
#pragma unroll
          for (int ni = 0; ni < 3; ++ni)
            vacc[mi][ni] = __builtin_amdgcn_mfma_f32_16x16x32_bf16(af[mi], bfr[ni], vacc[mi][ni], 0, 0, 0);
      }
    }
    __syncthreads();   // all K/X reads of phase B drained
    // ---- Phase B2: write P and VOt into the dead K region (+tail)
    if (wave < 4) {
      int i = wave * 16 + l15;
#pragma unroll
      for (int mj = 0; mj < 4; ++mj)
        *(bf16x4*)&Pl[i * ULD + mj * 16 + lg * 4] = psave[mj];
    } else {
      const int wv = wave - 4;
      const float* bu_h = bu + h * CH;
#pragma unroll
      for (int ni = 0; ni < 3; ++ni) {
        int c = (wv * 3 + ni) * 16 + l15;
        float bb = bu_h[c];
#pragma unroll
        for (int mi = 0; mi < 4; ++mi) {
          int s0 = mi * 16 + lg * 4;
          bf16x4 pk = { (bf16_t)(vacc[mi][ni][0] + bb), (bf16_t)(vacc[mi][ni][1] + bb),
                        (bf16_t)(vacc[mi][ni][2] + bb), (bf16_t)(vacc[mi][ni][3] + bb) };
          *(bf16x4*)&VOtl[c * ULD + s0] = pk;
        }
      }
    }
    __syncthreads();
    // ---- Phase Y: yacc[c,t] += sum_s VOt[c,s] P[t,s]
    {
#pragma unroll
      for (int ks = 0; ks < 2; ++ks) {
        bf16x8 af[3], bfr[2];
#pragma unroll
        for (int mi = 0; mi < 3; ++mi)
          af[mi] = *(const bf16x8*)&VOtl[((wc * 3 + mi) * 16 + l15) * ULD + ks * 32 + lg * 8];
#pragma unroll
        for (int ni = 0; ni < 2; ++ni)
          bfr[ni] = *(const bf16x8*)&Pl[((wt * 2 + ni) * 16 + l15) * ULD + ks * 32 + lg * 8];
#pragma unroll
        for (int mi = 0; mi < 3; ++mi)
#pragma unroll
          for (int ni = 0; ni < 2; ++ni)
            yacc[mi][ni] = __builtin_amdgcn_mfma_f32_16x16x32_bf16(af[mi], bfr[ni], yacc[mi][ni], 0, 0, 0);
      }
    }
  }

  // ---- epilogue: +bo, plain-reshape merge + roll(+3,+3), packed f32x4 stores
#pragma unroll
  for (int ni = 0; ni < 2; ++ni) {
    int t = (wt * 2 + ni) * 16 + l15;
    if (t < 49) {
      int pos = rem * 49 + t;
      int hp = pos / 112, wp = pos % 112;
      hp += SHIFT; if (hp >= HW) hp -= HW;
      wp += SHIFT; if (wp >= HW) wp -= HW;
      float* op = out + (((b * HW + hp) * HW) + wp) * CH;
#pragma unroll
      for (int mi = 0; mi < 3; ++mi) {
        int c0 = (wc * 3 + mi) * 16 + lg * 4;
        f32x4 v = yacc[mi][ni];
        v[0] += bo[c0]; v[1] += bo[c0 + 1]; v[2] += bo[c0 + 2]; v[3] += bo[c0 + 3];
        *(f32x4*)&op[c0] = v;
      }
    }
  }
}

extern "C" void kernel_launch(void* const* d_in, const int* in_sizes, int n_in,
                              void* d_out, int out_size, void* d_ws, size_t ws_size,
                              hipStream_t stream) {
  const float* x  = (const float*)d_in[0];
  const float* Wq = (const float*)d_in[1];
  const float* bq = (const float*)d_in[2];
  const float* Wk = (const float*)d_in[3];
  const float* bk = (const float*)d_in[4];
  const float* Wv = (const float*)d_in[5];
  const float* bv = (const float*)d_in[6];
  const float* Wo = (const float*)d_in[7];
  const float* bo = (const float*)d_in[8];
  float* out = (float*)d_out;
  bf16_t* wts = (bf16_t*)d_ws;                        // 1.33 MB
  float*  bu  = (float*)((char*)d_ws + BU_OFF_BYTES); // 4.6 KB

  const int per = NH * CH * CH;
  prep_w<<<(2 * per + 255) / 256, 256, 0, stream>>>(Wq, Wk, wts);
  prep_u<<<NH * CH, CH, 0, stream>>>(Wv, Wo, wts + 2 * per);
  prep_bu<<<NH, CH, 0, stream>>>(bv, Wo, bu);

  (void)hipFuncSetAttribute((const void*)swin_fused,
                            hipFuncAttributeMaxDynamicSharedMemorySize, LDS_BYTES);
  swin_fused<<<dim3(4096), dim3(512), LDS_BYTES, stream>>>(x, bq, bk, bo, wts, bu, out);
}

// Round 5
// 2611.877 us; speedup vs baseline: 1.0941x; 1.0941x over previous
//
#include <hip/hip_runtime.h>
#include <hip/hip_bf16.h>

typedef __bf16 bf16_t;
typedef __bf16 bf16x4 __attribute__((ext_vector_type(4)));
typedef __bf16 bf16x8 __attribute__((ext_vector_type(8)));
typedef float  f32x4  __attribute__((ext_vector_type(4)));

#define NH    6
#define CH    192
#define HW    112
#define SHIFT 3

// LDS strides (bf16 elems). XLD=200 -> 400B row step; ULD=72 -> 144B row step.
#define XLD 200
#define ULD 72

#define X_OFF   0
#define K_OFF   (64 * XLD)            // 12800
// P/VOt overlay the dead K region after the B2 barrier; VOt tail extends past K.
#define P_OFF   K_OFF                 // 64 x ULD   = 4608 elems
#define VOT_OFF (K_OFF + 64 * ULD)    // 192 x ULD  = 13824 elems
#define LDS_ELEMS (VOT_OFF + 192 * ULD)  // 31232
#define LDS_BYTES (LDS_ELEMS * 2)        // 62464 B -> 2 blocks/CU

// ws layout: wts[0]=Wq^T, wts[1]=Wk^T, wts[2]=U^T (each NH*CH*CH bf16), then bu f32[NH*CH]
#define BU_OFF_BYTES (3 * NH * CH * CH * 2)

// ---- prep: Wq/Wk transposed to bf16 ---------------------------------------
__global__ void prep_w(const float* __restrict__ Wq, const float* __restrict__ Wk,
                       bf16_t* __restrict__ out) {
  int idx = blockIdx.x * 256 + threadIdx.x;
  const int per = NH * CH * CH;
  if (idx >= 2 * per) return;
  int m = idx / per, r = idx % per;
  int h = r / (CH * CH), r2 = r % (CH * CH);
  int a = r2 / CH, k = r2 % CH;
  const float* W = m ? Wk : Wq;
  out[idx] = (bf16_t)W[(k * NH + h) * CH + a];   // wts[m][h][d_out][c_in]
}

// ---- prep: U^h = Wv^h x Wo^h (value/out-proj fusion), stored U^T[c_out][c_in]
__global__ void prep_u(const float* __restrict__ Wv, const float* __restrict__ Wo,
                       bf16_t* __restrict__ u_out) {
  __shared__ float wv_row[CH];
  int h = blockIdx.x / CH, ci = blockIdx.x % CH;
  int t = threadIdx.x;                            // c_out
  wv_row[t] = Wv[(ci * NH + h) * CH + t];
  __syncthreads();
  float acc = 0.f;
  for (int d = 0; d < CH; ++d)
    acc += wv_row[d] * Wo[(h * CH + d) * CH + t];
  u_out[(h * CH + t) * CH + ci] = (bf16_t)acc;
}

// ---- prep: bu^h = bv^h x Wo^h ---------------------------------------------
__global__ void prep_bu(const float* __restrict__ bv, const float* __restrict__ Wo,
                        float* __restrict__ bu) {
  int h = blockIdx.x, c = threadIdx.x;
  float acc = 0.f;
  for (int d = 0; d < CH; ++d)
    acc += bv[h * CH + d] * Wo[(h * CH + d) * CH + c];
  bu[h * CH + c] = acc;
}

// ---- fused swin block: one workgroup per 7x7 window, 8 waves, 2 blocks/CU --
__global__ __launch_bounds__(512, 2) void swin_fused(
    const float* __restrict__ x,
    const float* __restrict__ bq, const float* __restrict__ bk,
    const float* __restrict__ bo,
    const bf16_t* __restrict__ wts, const float* __restrict__ bu,
    float* __restrict__ out) {
  extern __shared__ char smem_raw[];
  bf16_t* lds  = (bf16_t*)smem_raw;
  bf16_t* Xl   = lds + X_OFF;
  bf16_t* Kl   = lds + K_OFF;
  bf16_t* Pl   = lds + P_OFF;     // overlay (valid after B2)
  bf16_t* VOtl = lds + VOT_OFF;   // overlay (valid after B2)

  const int tid  = threadIdx.x;
  const int wave = tid >> 6;           // 0..7
  const int lane = tid & 63;
  const int l15  = lane & 15;
  const int lg   = lane >> 4;          // 0..3

  const int blk = blockIdx.x;
  const int b   = blk >> 8;
  const int rem = blk & 255;
  const int wi  = rem >> 4, wj = rem & 15;

  // zero pad rows 49..63 of X
  for (int idx = tid; idx < 15 * 100; idx += 512) {
    int row = 49 + idx / 100, c2 = (idx % 100) * 2;
    *(unsigned int*)&Xl[row * XLD + c2] = 0u;
  }
  // stage window tokens (roll -3,-3 folded into the gather), f32 -> bf16
  for (int idx = tid; idx < 49 * 48; idx += 512) {
    int t = idx / 48, q4 = idx % 48;
    int hs = wi * 7 + t / 7 + SHIFT; if (hs >= HW) hs -= HW;
    int ws2 = wj * 7 + t % 7 + SHIFT; if (ws2 >= HW) ws2 -= HW;
    const float4 v = *(const float4*)&x[(((b * HW + hs) * HW) + ws2) * CH + q4 * 4];
    bf16x4 pk = { (bf16_t)v.x, (bf16_t)v.y, (bf16_t)v.z, (bf16_t)v.w };
    *(bf16x4*)&Xl[t * XLD + q4 * 4] = pk;
  }

  const int wc = wave & 3;             // phase-Y c-block (3 tiles each)
  const int wt = wave >> 2;            // phase-Y t-block (2 tiles each)
  f32x4 yacc[3][2] = {};               // persistent output accumulators

  for (int h = 0; h < NH; ++h) {
    __syncthreads();
    // ---- Phase A: waves 0-3: Q self-tile into REGISTERS (no LDS);
    //               waves 4-7: K^T-GEMM into LDS.
    bf16x4 qf[12];                     // Q[t=wave*16+l15][d=md*16+lg*4+r]
    if (wave < 4) {
      const bf16_t* wq_p = wts + (h * CH * CH);
      f32x4 accq[12] = {};
#pragma unroll
      for (int ks = 0; ks < 6; ++ks) {
        bf16x8 bfr = *(const bf16x8*)&Xl[(wave * 16 + l15) * XLD + ks * 32 + lg * 8];
#pragma unroll
        for (int md = 0; md < 12; ++md) {
          bf16x8 af = *(const bf16x8*)&wq_p[(md * 16 + l15) * CH + ks * 32 + lg * 8];
          accq[md] = __builtin_amdgcn_mfma_f32_16x16x32_bf16(af, bfr, accq[md], 0, 0, 0);
        }
      }
#pragma unroll
      for (int md = 0; md < 12; ++md) {
        const f32x4 bb = *(const f32x4*)&bq[h * CH + md * 16 + lg * 4];
        bf16x4 pk = { (bf16_t)(accq[md][0] + bb[0]), (bf16_t)(accq[md][1] + bb[1]),
                      (bf16_t)(accq[md][2] + bb[2]), (bf16_t)(accq[md][3] + bb[3]) };
        qf[md] = pk;
      }
    } else {
      const int w2 = wave - 4;
      const bf16_t* wk_p = wts + ((NH + h) * CH * CH);
      const float* bias = bk + h * CH;
      f32x4 acc[3][4] = {};
#pragma unroll
      for (int ks = 0; ks < 6; ++ks) {
        bf16x8 af[3], bfr[4];
#pragma unroll
        for (int mi = 0; mi < 3; ++mi) {
          int d = (w2 * 3 + mi) * 16 + l15;
          af[mi] = *(const bf16x8*)&wk_p[d * CH + ks * 32 + lg * 8];
        }
#pragma unroll
        for (int ni = 0; ni < 4; ++ni)
          bfr[ni] = *(const bf16x8*)&Xl[(ni * 16 + l15) * XLD + ks * 32 + lg * 8];
#pragma unroll
        for (int mi = 0; mi < 3; ++mi)
#pragma unroll
          for (int ni = 0; ni < 4; ++ni)
            acc[mi][ni] = __builtin_amdgcn_mfma_f32_16x16x32_bf16(af[mi], bfr[ni], acc[mi][ni], 0, 0, 0);
      }
#pragma unroll
      for (int mi = 0; mi < 3; ++mi) {
        int d0 = (w2 * 3 + mi) * 16 + lg * 4;
        float b0 = bias[d0], b1 = bias[d0 + 1], b2 = bias[d0 + 2], b3 = bias[d0 + 3];
#pragma unroll
        for (int ni = 0; ni < 4; ++ni) {
          int t = ni * 16 + l15;
          bf16x4 pk = { (bf16_t)(acc[mi][ni][0] + b0), (bf16_t)(acc[mi][ni][1] + b1),
                        (bf16_t)(acc[mi][ni][2] + b2), (bf16_t)(acc[mi][ni][3] + b3) };
          *(bf16x4*)&Kl[t * XLD + d0] = pk;
        }
      }
    }
    __syncthreads();
    // ---- Phase B: waves 0-3: scores + in-register softmax (Q from regs,
    //               K read with the MATCHING permuted k-slot order);
    //               waves 4-7: VO-GEMM (X x U^h) into registers.
    f32x4 vacc[4][3] = {};
    bf16x4 psave[4];
    const bf16_t* U_h = wts + ((2 * NH + h) * CH * CH);
    if (wave < 4) {
      f32x4 sacc[4] = {};
#pragma unroll
      for (int ks = 0; ks < 6; ++ks) {
        // B-frag: slots 0-3 = Q[t][ks*32+lg*4+r], slots 4-7 = Q[t][ks*32+16+lg*4+r]
        bf16x8 bq8 = __builtin_shufflevector(qf[2 * ks], qf[2 * ks + 1], 0, 1, 2, 3, 4, 5, 6, 7);
#pragma unroll
        for (int mj = 0; mj < 4; ++mj) {
          // A-frag with the SAME k-slot permutation (two b64 reads, d and d+16)
          const bf16_t* kr = &Kl[(mj * 16 + l15) * XLD + ks * 32 + lg * 4];
          bf16x4 k0 = *(const bf16x4*)kr;
          bf16x4 k1 = *(const bf16x4*)(kr + 16);
          bf16x8 ak = __builtin_shufflevector(k0, k1, 0, 1, 2, 3, 4, 5, 6, 7);
          sacc[mj] = __builtin_amdgcn_mfma_f32_16x16x32_bf16(ak, bq8, sacc[mj], 0, 0, 0);
        }
      }
      const float scale = 0.07216878364870322f;  // 1/sqrt(192)
      float mx = -1e30f;
#pragma unroll
      for (int mj = 0; mj < 4; ++mj)
#pragma unroll
        for (int r = 0; r < 4; ++r) {
          int j = mj * 16 + lg * 4 + r;
          if (j < 49) mx = fmaxf(mx, sacc[mj][r]);
        }
      mx = fmaxf(mx, __shfl_xor(mx, 16));
      mx = fmaxf(mx, __shfl_xor(mx, 32));
      float p[4][4];
      float sum = 0.f;
#pragma unroll
      for (int mj = 0; mj < 4; ++mj)
#pragma unroll
        for (int r = 0; r < 4; ++r) {
          int j = mj * 16 + lg * 4 + r;
          float e = (j < 49) ? __expf((sacc[mj][r] - mx) * scale) : 0.f;
          p[mj][r] = e;
          sum += e;
        }
      sum += __shfl_xor(sum, 16);
      sum += __shfl_xor(sum, 32);
      float inv = 1.f / sum;
#pragma unroll
      for (int mj = 0; mj < 4; ++mj) {
        bf16x4 pk = { (bf16_t)(p[mj][0] * inv), (bf16_t)(p[mj][1] * inv),
                      (bf16_t)(p[mj][2] * inv), (bf16_t)(p[mj][3] * inv) };
        psave[mj] = pk;
      }
    } else {
      const int wv = wave - 4;
#pragma unroll
      for (int ks = 0; ks < 6; ++ks) {
        bf16x8 af[4], bfr[3];
#pragma unroll
        for (int mi = 0; mi < 4; ++mi)
          af[mi] = *(const bf16x8*)&Xl[(mi * 16 + l15) * XLD + ks * 32 + lg * 8];
#pragma unroll
        for (int ni = 0; ni < 3; ++ni) {
          int c = (wv * 3 + ni) * 16 + l15;
          bfr[ni] = *(const bf16x8*)&U_h[c * CH + ks * 32 + lg * 8];
        }
#pragma unroll
        for (int mi = 0; mi < 4; ++mi)
#pragma unroll
          for (int ni = 0; ni < 3; ++ni)
            vacc[mi][ni] = __builtin_amdgcn_mfma_f32_16x16x32_bf16(af[mi], bfr[ni], vacc[mi][ni], 0, 0, 0);
      }
    }
    __syncthreads();   // all K/X reads of phase B drained
    // ---- Phase B2: write P and VOt into the dead K region (+tail)
    if (wave < 4) {
      int i = wave * 16 + l15;
#pragma unroll
      for (int mj = 0; mj < 4; ++mj)
        *(bf16x4*)&Pl[i * ULD + mj * 16 + lg * 4] = psave[mj];
    } else {
      const int wv = wave - 4;
      const float* bu_h = bu + h * CH;
#pragma unroll
      for (int ni = 0; ni < 3; ++ni) {
        int c = (wv * 3 + ni) * 16 + l15;
        float bb = bu_h[c];
#pragma unroll
        for (int mi = 0; mi < 4; ++mi) {
          int s0 = mi * 16 + lg * 4;
          bf16x4 pk = { (bf16_t)(vacc[mi][ni][0] + bb), (bf16_t)(vacc[mi][ni][1] + bb),
                        (bf16_t)(vacc[mi][ni][2] + bb), (bf16_t)(vacc[mi][ni][3] + bb) };
          *(bf16x4*)&VOtl[c * ULD + s0] = pk;
        }
      }
    }
    __syncthreads();
    // ---- Phase Y: yacc[c,t] += sum_s VOt[c,s] P[t,s]
    {
#pragma unroll
      for (int ks = 0; ks < 2; ++ks) {
        bf16x8 af[3], bfr[2];
#pragma unroll
        for (int mi = 0; mi < 3; ++mi)
          af[mi] = *(const bf16x8*)&VOtl[((wc * 3 + mi) * 16 + l15) * ULD + ks * 32 + lg * 8];
#pragma unroll
        for (int ni = 0; ni < 2; ++ni)
          bfr[ni] = *(const bf16x8*)&Pl[((wt * 2 + ni) * 16 + l15) * ULD + ks * 32 + lg * 8];
#pragma unroll
        for (int mi = 0; mi < 3; ++mi)
#pragma unroll
          for (int ni = 0; ni < 2; ++ni)
            yacc[mi][ni] = __builtin_amdgcn_mfma_f32_16x16x32_bf16(af[mi], bfr[ni], yacc[mi][ni], 0, 0, 0);
      }
    }
  }

  // ---- epilogue: +bo, plain-reshape merge + roll(+3,+3), packed f32x4 stores
#pragma unroll
  for (int ni = 0; ni < 2; ++ni) {
    int t = (wt * 2 + ni) * 16 + l15;
    if (t < 49) {
      int pos = rem * 49 + t;
      int hp = pos / 112, wp = pos % 112;
      hp += SHIFT; if (hp >= HW) hp -= HW;
      wp += SHIFT; if (wp >= HW) wp -= HW;
      float* op = out + (((b * HW + hp) * HW) + wp) * CH;
#pragma unroll
      for (int mi = 0; mi < 3; ++mi) {
        int c0 = (wc * 3 + mi) * 16 + lg * 4;
        f32x4 v = yacc[mi][ni];
        v[0] += bo[c0]; v[1] += bo[c0 + 1]; v[2] += bo[c0 + 2]; v[3] += bo[c0 + 3];
        *(f32x4*)&op[c0] = v;
      }
    }
  }
}

extern "C" void kernel_launch(void* const* d_in, const int* in_sizes, int n_in,
                              void* d_out, int out_size, void* d_ws, size_t ws_size,
                              hipStream_t stream) {
  const float* x  = (const float*)d_in[0];
  const float* Wq = (const float*)d_in[1];
  const float* bq = (const float*)d_in[2];
  const float* Wk = (const float*)d_in[3];
  const float* bk = (const float*)d_in[4];
  const float* Wv = (const float*)d_in[5];
  const float* bv = (const float*)d_in[6];
  const float* Wo = (const float*)d_in[7];
  const float* bo = (const float*)d_in[8];
  float* out = (float*)d_out;
  bf16_t* wts = (bf16_t*)d_ws;                        // 1.33 MB
  float*  bu  = (float*)((char*)d_ws + BU_OFF_BYTES); // 4.6 KB

  const int per = NH * CH * CH;
  prep_w<<<(2 * per + 255) / 256, 256, 0, stream>>>(Wq, Wk, wts);
  prep_u<<<NH * CH, CH, 0, stream>>>(Wv, Wo, wts + 2 * per);
  prep_bu<<<NH, CH, 0, stream>>>(bv, Wo, bu);

  (void)hipFuncSetAttribute((const void*)swin_fused,
                            hipFuncAttributeMaxDynamicSharedMemorySize, LDS_BYTES);
  swin_fused<<<dim3(4096), dim3(512), LDS_BYTES, stream>>>(x, bq, bk, bo, wts, bu, out);
}

// Round 6
// 884.055 us; speedup vs baseline: 3.2325x; 2.9544x over previous
//
#include <hip/hip_runtime.h>
#include <hip/hip_bf16.h>

typedef __bf16 bf16_t;
typedef __bf16 bf16x4 __attribute__((ext_vector_type(4)));
typedef __bf16 bf16x8 __attribute__((ext_vector_type(8)));
typedef float  f32x4  __attribute__((ext_vector_type(4)));

#define NH    6
#define CH    192
#define HW    112
#define SHIFT 3

// LDS strides (bf16 elems). XLD=200 -> 400B row step (2-way on b128, free);
// ULD=72 -> 144B row step (same class).
#define XLD 200
#define ULD 72

#define X_OFF   0
#define T_OFF   (64 * XLD)            // 12800; T rows 0..48 written, reads to row 63 spill into overlay (junk, outputs ignored)
#define P_OFF   T_OFF                 // overlay after S-phase: P [64][ULD] = 4608
#define VOT_OFF (T_OFF + 64 * ULD)    // VOt [192][ULD] = 13824
#define LDS_ELEMS (VOT_OFF + 192 * ULD)  // 31232
#define LDS_BYTES (LDS_ELEMS * 2)        // 62464 B

// ws layout: Gt (NH*CH*CH bf16) | U^T (NH*CH*CH bf16) | bu f32[NH*CH] | w1 f32[NH*CH]
#define U_OFF_ELEMS  (NH * CH * CH)
#define BU_OFF_BYTES (2 * NH * CH * CH * 2)
#define W1_OFF_BYTES (BU_OFF_BYTES + NH * CH * 4)

// ---- prep: Gt[h][c'][c] = sum_d Wk[c',h,d] * Wq[c,h,d]  (= Wk Wq^T) -------
__global__ void prep_gt(const float* __restrict__ Wq, const float* __restrict__ Wk,
                        bf16_t* __restrict__ gt) {
  __shared__ float wk_row[CH];
  int h = blockIdx.x / CH, cp = blockIdx.x % CH;
  int c = threadIdx.x;
  wk_row[c] = Wk[(cp * NH + h) * CH + c];
  __syncthreads();
  float acc = 0.f;
  for (int d = 0; d < CH; ++d)
    acc += wk_row[d] * Wq[(c * NH + h) * CH + d];
  gt[(h * CH + cp) * CH + c] = (bf16_t)acc;
}

// ---- prep: U^h = Wv^h x Wo^h (value/out-proj fusion), stored U^T[c_out][c_in]
__global__ void prep_u(const float* __restrict__ Wv, const float* __restrict__ Wo,
                       bf16_t* __restrict__ u_out) {
  __shared__ float wv_row[CH];
  int h = blockIdx.x / CH, ci = blockIdx.x % CH;
  int t = threadIdx.x;                            // c_out
  wv_row[t] = Wv[(ci * NH + h) * CH + t];
  __syncthreads();
  float acc = 0.f;
  for (int d = 0; d < CH; ++d)
    acc += wv_row[d] * Wo[(h * CH + d) * CH + t];
  u_out[(h * CH + t) * CH + ci] = (bf16_t)acc;
}

// ---- prep: bu^h = bv^h x Wo^h ---------------------------------------------
__global__ void prep_bu(const float* __restrict__ bv, const float* __restrict__ Wo,
                        float* __restrict__ bu) {
  int h = blockIdx.x, c = threadIdx.x;
  float acc = 0.f;
  for (int d = 0; d < CH; ++d)
    acc += bv[h * CH + d] * Wo[(h * CH + d) * CH + c];
  bu[h * CH + c] = acc;
}

// ---- prep: w1^h[c'] = sum_d Wk[c',h,d] * bq[h,d]  (softmax-relevant bias) --
__global__ void prep_w1(const float* __restrict__ Wk, const float* __restrict__ bq,
                        float* __restrict__ w1) {
  int h = blockIdx.x, cp = threadIdx.x;
  float acc = 0.f;
  for (int d = 0; d < CH; ++d)
    acc += Wk[(cp * NH + h) * CH + d] * bq[h * CH + d];
  w1[h * CH + cp] = acc;
}

// ---- fused swin block: one workgroup per 7x7 window, 8 waves ---------------
__global__ __launch_bounds__(512, 2) void swin_fused(
    const float* __restrict__ x,
    const float* __restrict__ bo,
    const bf16_t* __restrict__ wts,     // Gt | U
    const float* __restrict__ bu, const float* __restrict__ w1,
    float* __restrict__ out) {
  extern __shared__ char smem_raw[];
  bf16_t* lds  = (bf16_t*)smem_raw;
  bf16_t* Xl   = lds + X_OFF;
  bf16_t* Tl   = lds + T_OFF;
  bf16_t* Pl   = lds + P_OFF;     // overlay (valid after B2)
  bf16_t* VOtl = lds + VOT_OFF;   // overlay (valid after B2)

  const int tid  = threadIdx.x;
  const int wave = tid >> 6;           // 0..7
  const int lane = tid & 63;
  const int l15  = lane & 15;
  const int lg   = lane >> 4;          // 0..3

  const int blk = blockIdx.x;
  const int b   = blk >> 8;
  const int rem = blk & 255;
  const int wi  = rem >> 4, wj = rem & 15;

  // zero pad rows 49..63 of X
  for (int idx = tid; idx < 15 * 100; idx += 512) {
    int row = 49 + idx / 100, c2 = (idx % 100) * 2;
    *(unsigned int*)&Xl[row * XLD + c2] = 0u;
  }
  // stage window tokens (roll -3,-3 folded into the gather), f32 -> bf16
  for (int idx = tid; idx < 49 * 48; idx += 512) {
    int t = idx / 48, q4 = idx % 48;
    int hs = wi * 7 + t / 7 + SHIFT; if (hs >= HW) hs -= HW;
    int ws2 = wj * 7 + t % 7 + SHIFT; if (ws2 >= HW) ws2 -= HW;
    const float4 v = *(const float4*)&x[(((b * HW + hs) * HW) + ws2) * CH + q4 * 4];
    bf16x4 pk = { (bf16_t)v.x, (bf16_t)v.y, (bf16_t)v.z, (bf16_t)v.w };
    *(bf16x4*)&Xl[t * XLD + q4 * 4] = pk;
  }

  const int wc = wave & 3;             // phase-Y c-block (3 tiles each)
  const int wt = wave >> 2;            // phase-Y t-block (2 tiles each)
  f32x4 yacc[3][2] = {};               // persistent output accumulators

  for (int h = 0; h < NH; ++h) {
    __syncthreads();
    // ---- Phase T (all 8 waves): T = X Gt^T rows; T[i][c'] = sum_c X[i,c] Gt[c',c]
    // wave owns 3 c'-tiles x 2 i-tiles; packed b64 writes into T[i][c'] (i<49).
    {
      const bf16_t* gt = wts + h * CH * CH;
      const int wm = (wave & 3) * 3, wn = (wave >> 2) * 2;
      f32x4 acc[3][2] = {};
#pragma unroll
      for (int ks = 0; ks < 6; ++ks) {
        bf16x8 af[3], bfr[2];
#pragma unroll
        for (int mi = 0; mi < 3; ++mi)
          af[mi] = *(const bf16x8*)&gt[((wm + mi) * 16 + l15) * CH + ks * 32 + lg * 8];
#pragma unroll
        for (int ni = 0; ni < 2; ++ni)
          bfr[ni] = *(const bf16x8*)&Xl[((wn + ni) * 16 + l15) * XLD + ks * 32 + lg * 8];
#pragma unroll
        for (int mi = 0; mi < 3; ++mi)
#pragma unroll
          for (int ni = 0; ni < 2; ++ni)
            acc[mi][ni] = __builtin_amdgcn_mfma_f32_16x16x32_bf16(af[mi], bfr[ni], acc[mi][ni], 0, 0, 0);
      }
      const float* w1h = w1 + h * CH;
#pragma unroll
      for (int mi = 0; mi < 3; ++mi) {
        int cp0 = (wm + mi) * 16 + lg * 4;
        const f32x4 ww = *(const f32x4*)&w1h[cp0];
#pragma unroll
        for (int ni = 0; ni < 2; ++ni) {
          int i = (wn + ni) * 16 + l15;
          if (i < 49) {
            bf16x4 pk = { (bf16_t)(acc[mi][ni][0] + ww[0]), (bf16_t)(acc[mi][ni][1] + ww[1]),
                          (bf16_t)(acc[mi][ni][2] + ww[2]), (bf16_t)(acc[mi][ni][3] + ww[3]) };
            *(bf16x4*)&Tl[i * XLD + cp0] = pk;
          }
        }
      }
    }
    __syncthreads();
    // ---- Phase S/VO: waves 0-3: scores S[i,j] = sum_c' X[j,c'] T[i,c'] +
    //      in-register softmax, plus 1 VO c-tile; waves 4-7: 2 VO c-tiles each.
    //      VO[c][s] = sum_c X[s,c] U^T[c_out,c]  (X rows shared as A-frags).
    bf16x4 psave[4];
    f32x4 vacc[2][4] = {};
    const bf16_t* U_h = wts + U_OFF_ELEMS + h * CH * CH;
    if (wave < 4) {
      const int it = wave, ct = 8 + wave;
      f32x4 sacc[4] = {};
#pragma unroll
      for (int ks = 0; ks < 6; ++ks) {
        bf16x8 af[4];
#pragma unroll
        for (int mi = 0; mi < 4; ++mi)
          af[mi] = *(const bf16x8*)&Xl[(mi * 16 + l15) * XLD + ks * 32 + lg * 8];
        bf16x8 bt = *(const bf16x8*)&Tl[(it * 16 + l15) * XLD + ks * 32 + lg * 8];
        bf16x8 bu8 = *(const bf16x8*)&U_h[(ct * 16 + l15) * CH + ks * 32 + lg * 8];
#pragma unroll
        for (int mj = 0; mj < 4; ++mj)
          sacc[mj] = __builtin_amdgcn_mfma_f32_16x16x32_bf16(af[mj], bt, sacc[mj], 0, 0, 0);
#pragma unroll
        for (int mi = 0; mi < 4; ++mi)
          vacc[0][mi] = __builtin_amdgcn_mfma_f32_16x16x32_bf16(af[mi], bu8, vacc[0][mi], 0, 0, 0);
      }
      const float scale = 0.07216878364870322f;  // 1/sqrt(192)
      float mx = -1e30f;
#pragma unroll
      for (int mj = 0; mj < 4; ++mj)
#pragma unroll
        for (int r = 0; r < 4; ++r) {
          int j = mj * 16 + lg * 4 + r;
          if (j < 49) mx = fmaxf(mx, sacc[mj][r]);
        }
      mx = fmaxf(mx, __shfl_xor(mx, 16));
      mx = fmaxf(mx, __shfl_xor(mx, 32));
      float p[4][4];
      float sum = 0.f;
#pragma unroll
      for (int mj = 0; mj < 4; ++mj)
#pragma unroll
        for (int r = 0; r < 4; ++r) {
          int j = mj * 16 + lg * 4 + r;
          float e = (j < 49) ? __expf((sacc[mj][r] - mx) * scale) : 0.f;
          p[mj][r] = e;
          sum += e;
        }
      sum += __shfl_xor(sum, 16);
      sum += __shfl_xor(sum, 32);
      float inv = 1.f / sum;
#pragma unroll
      for (int mj = 0; mj < 4; ++mj) {
        bf16x4 pk = { (bf16_t)(p[mj][0] * inv), (bf16_t)(p[mj][1] * inv),
                      (bf16_t)(p[mj][2] * inv), (bf16_t)(p[mj][3] * inv) };
        psave[mj] = pk;
      }
    } else {
      const int c0 = (wave - 4) * 2;
#pragma unroll
      for (int ks = 0; ks < 6; ++ks) {
        bf16x8 af[4], bfu[2];
#pragma unroll
        for (int mi = 0; mi < 4; ++mi)
          af[mi] = *(const bf16x8*)&Xl[(mi * 16 + l15) * XLD + ks * 32 + lg * 8];
#pragma unroll
        for (int cj = 0; cj < 2; ++cj)
          bfu[cj] = *(const bf16x8*)&U_h[((c0 + cj) * 16 + l15) * CH + ks * 32 + lg * 8];
#pragma unroll
        for (int cj = 0; cj < 2; ++cj)
#pragma unroll
          for (int mi = 0; mi < 4; ++mi)
            vacc[cj][mi] = __builtin_amdgcn_mfma_f32_16x16x32_bf16(af[mi], bfu[cj], vacc[cj][mi], 0, 0, 0);
      }
    }
    __syncthreads();   // all T/X reads of phase S/VO drained
    // ---- Phase B2: write P and VOt into the dead T region
    const float* bu_h = bu + h * CH;
    if (wave < 4) {
      int i = wave * 16 + l15;
#pragma unroll
      for (int mj = 0; mj < 4; ++mj)
        *(bf16x4*)&Pl[i * ULD + mj * 16 + lg * 4] = psave[mj];
      int c = (8 + wave) * 16 + l15;
      float bb = bu_h[c];
#pragma unroll
      for (int mi = 0; mi < 4; ++mi) {
        int s0 = mi * 16 + lg * 4;
        bf16x4 pk = { (bf16_t)(vacc[0][mi][0] + bb), (bf16_t)(vacc[0][mi][1] + bb),
                      (bf16_t)(vacc[0][mi][2] + bb), (bf16_t)(vacc[0][mi][3] + bb) };
        *(bf16x4*)&VOtl[c * ULD + s0] = pk;
      }
    } else {
      const int c0 = (wave - 4) * 2;
#pragma unroll
      for (int cj = 0; cj < 2; ++cj) {
        int c = (c0 + cj) * 16 + l15;
        float bb = bu_h[c];
#pragma unroll
        for (int mi = 0; mi < 4; ++mi) {
          int s0 = mi * 16 + lg * 4;
          bf16x4 pk = { (bf16_t)(vacc[cj][mi][0] + bb), (bf16_t)(vacc[cj][mi][1] + bb),
                        (bf16_t)(vacc[cj][mi][2] + bb), (bf16_t)(vacc[cj][mi][3] + bb) };
          *(bf16x4*)&VOtl[c * ULD + s0] = pk;
        }
      }
    }
    __syncthreads();
    // ---- Phase Y: yacc[c,t] += sum_s VOt[c,s] P[t,s]
    {
#pragma unroll
      for (int ks = 0; ks < 2; ++ks) {
        bf16x8 af[3], bfr[2];
#pragma unroll
        for (int mi = 0; mi < 3; ++mi)
          af[mi] = *(const bf16x8*)&VOtl[((wc * 3 + mi) * 16 + l15) * ULD + ks * 32 + lg * 8];
#pragma unroll
        for (int ni = 0; ni < 2; ++ni)
          bfr[ni] = *(const bf16x8*)&Pl[((wt * 2 + ni) * 16 + l15) * ULD + ks * 32 + lg * 8];
#pragma unroll
        for (int mi = 0; mi < 3; ++mi)
#pragma unroll
          for (int ni = 0; ni < 2; ++ni)
            yacc[mi][ni] = __builtin_amdgcn_mfma_f32_16x16x32_bf16(af[mi], bfr[ni], yacc[mi][ni], 0, 0, 0);
      }
    }
  }

  // ---- epilogue: +bo, plain-reshape merge + roll(+3,+3), packed f32x4 stores
#pragma unroll
  for (int ni = 0; ni < 2; ++ni) {
    int t = (wt * 2 + ni) * 16 + l15;
    if (t < 49) {
      int pos = rem * 49 + t;
      int hp = pos / 112, wp = pos % 112;
      hp += SHIFT; if (hp >= HW) hp -= HW;
      wp += SHIFT; if (wp >= HW) wp -= HW;
      float* op = out + (((b * HW + hp) * HW) + wp) * CH;
#pragma unroll
      for (int mi = 0; mi < 3; ++mi) {
        int c0 = (wc * 3 + mi) * 16 + lg * 4;
        f32x4 v = yacc[mi][ni];
        v[0] += bo[c0]; v[1] += bo[c0 + 1]; v[2] += bo[c0 + 2]; v[3] += bo[c0 + 3];
        *(f32x4*)&op[c0] = v;
      }
    }
  }
}

extern "C" void kernel_launch(void* const* d_in, const int* in_sizes, int n_in,
                              void* d_out, int out_size, void* d_ws, size_t ws_size,
                              hipStream_t stream) {
  const float* x  = (const float*)d_in[0];
  const float* Wq = (const float*)d_in[1];
  const float* bq = (const float*)d_in[2];
  const float* Wk = (const float*)d_in[3];
  const float* Wv = (const float*)d_in[5];
  const float* bv = (const float*)d_in[6];
  const float* Wo = (const float*)d_in[7];
  const float* bo = (const float*)d_in[8];
  float* out = (float*)d_out;
  bf16_t* wts = (bf16_t*)d_ws;                        // Gt | U, 884 KB
  float*  bu  = (float*)((char*)d_ws + BU_OFF_BYTES);
  float*  w1  = (float*)((char*)d_ws + W1_OFF_BYTES);

  prep_gt<<<NH * CH, CH, 0, stream>>>(Wq, Wk, wts);
  prep_u<<<NH * CH, CH, 0, stream>>>(Wv, Wo, wts + U_OFF_ELEMS);
  prep_bu<<<NH, CH, 0, stream>>>(bv, Wo, bu);
  prep_w1<<<NH, CH, 0, stream>>>(Wk, bq, w1);

  (void)hipFuncSetAttribute((const void*)swin_fused,
                            hipFuncAttributeMaxDynamicSharedMemorySize, LDS_BYTES);
  swin_fused<<<dim3(4096), dim3(512), LDS_BYTES, stream>>>(x, bo, wts, bu, w1, out);
}